// Round 3
// baseline (1886.739 us; speedup 1.0000x reference)
//
#include <hip/hip_runtime.h>
#include <hip/hip_bf16.h>
#include <cstdint>
#include <cstddef>

// Inputs fp32, output fp32. Internal bf16 MFMA.
// R3 = R2 resubmission (R2 bench died on container infra; kernel audited for
// hang/OOB/launch-resource failure modes — clean). Structure: 256-tile BK=64
// 8-wave phase-split GEMMs (T3+T4 counted vmcnt(8), T2 both-sides XOR swizzle
// chunk^=row&7, T5 setprio around MFMA clusters).

#define S_ 2048
#define B_ 4
#define H_ 2048
#define F_ 1408
#define F2_ 2816
#define E_ 8
#define T_ 8192

typedef float f32x4 __attribute__((ext_vector_type(4)));
typedef short s16x8 __attribute__((ext_vector_type(8)));

#define WAITV8 asm volatile("s_waitcnt vmcnt(8)" ::: "memory")
#define WAITV0 asm volatile("s_waitcnt vmcnt(0)" ::: "memory")
#define LGKM0  asm volatile("s_waitcnt lgkmcnt(0)" ::: "memory")
#define SB()   __builtin_amdgcn_s_barrier()
#define SCB()  __builtin_amdgcn_sched_barrier(0)

__device__ __forceinline__ unsigned short f2b(float f) {
  union { unsigned int i; float f; } v; v.f = f;
  unsigned int r = v.i + 0x7FFFu + ((v.i >> 16) & 1u);
  return (unsigned short)(r >> 16);
}
__device__ __forceinline__ unsigned int pkbf(float lo, float hi) {
  __hip_bfloat162 h2 = __float22bfloat162_rn(make_float2(lo, hi));
  union { __hip_bfloat162 v; unsigned int u; } c; c.v = h2; return c.u;
}
__device__ __forceinline__ void gld16(const unsigned short* gp, unsigned short* lp) {
  __builtin_amdgcn_global_load_lds(
      (const __attribute__((address_space(1))) unsigned int*)gp,
      (__attribute__((address_space(3))) unsigned int*)lp, 16, 0, 0);
}
// swizzled fragment read: row r (128B rows), 16B-chunk c (0..7); slot = c ^ (r&7)
__device__ __forceinline__ s16x8 ldfrag(const unsigned short* base, int r, int c) {
  return *(const s16x8*)((const char*)base + r * 128 + (((c) ^ (r & 7)) << 4));
}

// ---------------- workspace layout (bytes) ----------------
// 0       : int counts[8]; 32: cursor[8]; 64: offs[8]
// 128     : int   eidx[2T]
// 65664   : float ewt[2T]
// 131200  : int   rowlist[2T]
// 196736  : float rowwt[2T]
// 262272  : bf16  g[2T][F]            (46137344)
// 46399616: bf16  xb[T][H]            (33554432)
// 79954048: bf16  w1t[E][2F][H]       (92274688)   k-major
// 172228736: bf16 w2t[E][H][F]        (46137344)   k-major
// total ~218.4 MB

__global__ void zero_kernel(int* ws_i) {
  if (threadIdx.x < 16) ws_i[threadIdx.x] = 0;
}

__global__ __launch_bounds__(256) void cvt_kernel(
    const float* __restrict__ src, unsigned short* __restrict__ dst, int n8) {
  int i = blockIdx.x * 256 + threadIdx.x;
  if (i >= n8) return;
  f32x4 a = *(const f32x4*)(src + (size_t)i * 8);
  f32x4 b = *(const f32x4*)(src + (size_t)i * 8 + 4);
  uint4 u;
  u.x = pkbf(a[0], a[1]); u.y = pkbf(a[2], a[3]);
  u.z = pkbf(b[0], b[1]); u.w = pkbf(b[2], b[3]);
  *(uint4*)(dst + (size_t)i * 8) = u;
}

// src[e][r][c] fp32 -> dst[e][c][r] bf16.  64x64 tiles, dims % 64 == 0.
__global__ __launch_bounds__(256) void tcvt_kernel(
    const float* __restrict__ src, unsigned short* __restrict__ dst,
    int rows, int cols) {
  int e = blockIdx.z;
  int c0 = blockIdx.x * 64, r0 = blockIdx.y * 64;
  const float* s = src + (size_t)e * rows * cols;
  unsigned short* d = dst + (size_t)e * rows * cols;
  __shared__ unsigned short Lt[64][72];
  int tid = threadIdx.x;
  int cl = tid & 63, w = tid >> 6;
#pragma unroll
  for (int i = 0; i < 16; i++) {
    int r = w * 16 + i;
    Lt[cl][r] = f2b(s[(size_t)(r0 + r) * cols + c0 + cl]);
  }
  __syncthreads();
  int cc = tid >> 3, hc = tid & 7;
#pragma unroll
  for (int j = 0; j < 2; j++) {
    int c = cc + j * 32;
    *(uint4*)&d[(size_t)(c0 + c) * rows + r0 + hc * 8] = *(uint4*)&Lt[c][hc * 8];
  }
}

// one wave per token: fp32 logits over 8 experts, softmax, top-2
__global__ __launch_bounds__(256) void gate_kernel(
    const float* __restrict__ x, const float* __restrict__ wg,
    int* __restrict__ counts, int* __restrict__ eidx, float* __restrict__ ewt) {
  int wave = threadIdx.x >> 6, lane = threadIdx.x & 63;
  int t = blockIdx.x * 4 + wave;
  int b = t >> 11, s = t & (S_ - 1);
  const float* xrow = x + (size_t)(s * B_ + b) * H_;
  float acc[E_];
#pragma unroll
  for (int e = 0; e < E_; e++) acc[e] = 0.f;
  for (int h0 = lane * 4; h0 < H_; h0 += 256) {
    f32x4 xa = *(const f32x4*)(xrow + h0);
#pragma unroll
    for (int e = 0; e < E_; e++) {
      f32x4 wa = *(const f32x4*)(wg + e * H_ + h0);
      acc[e] += xa[0] * wa[0] + xa[1] * wa[1] + xa[2] * wa[2] + xa[3] * wa[3];
    }
  }
#pragma unroll
  for (int e = 0; e < E_; e++)
    for (int off = 32; off; off >>= 1) acc[e] += __shfl_xor(acc[e], off, 64);
  if (lane == 0) {
    float m = acc[0];
#pragma unroll
    for (int e = 1; e < E_; e++) m = fmaxf(m, acc[e]);
    float ex[E_], ssum = 0.f;
#pragma unroll
    for (int e = 0; e < E_; e++) { ex[e] = __expf(acc[e] - m); ssum += ex[e]; }
    float sc[E_];
#pragma unroll
    for (int e = 0; e < E_; e++) sc[e] = ex[e] / ssum;
    int i1 = 0;
#pragma unroll
    for (int e = 1; e < E_; e++) if (sc[e] > sc[i1]) i1 = e;
    int i2 = (i1 == 0) ? 1 : 0;
#pragma unroll
    for (int e = 0; e < E_; e++) if (e != i1 && sc[e] > sc[i2]) i2 = e;
    float wsum = sc[i1] + sc[i2] + 1e-20f;
    eidx[2 * t] = i1;     ewt[2 * t] = sc[i1] / wsum;
    eidx[2 * t + 1] = i2; ewt[2 * t + 1] = sc[i2] / wsum;
    atomicAdd(&counts[i1], 1);
    atomicAdd(&counts[i2], 1);
  }
}

__global__ void scan_kernel(const int* __restrict__ counts, int* __restrict__ offs) {
  if (threadIdx.x == 0) {
    int run = 0;
    for (int e = 0; e < E_; e++) { offs[e] = run; run += counts[e]; }
  }
}

__global__ void assign_kernel(const int* __restrict__ eidx, const float* __restrict__ ewt,
                              const int* __restrict__ offs, int* __restrict__ cursor,
                              int* __restrict__ rowlist, float* __restrict__ rowwt) {
  int t = blockIdx.x * 256 + threadIdx.x;
  if (t >= T_) return;
#pragma unroll
  for (int k = 0; k < 2; k++) {
    int e = eidx[2 * t + k];
    int pos = atomicAdd(&cursor[e], 1);
    int slot = offs[e] + pos;
    rowlist[slot] = t;
    rowwt[slot] = ewt[2 * t + k];
  }
}

// GEMM1 + swiglu. grid (mt=32, ft=11, e=8). Tile 256 rows x 128 f-pairs
// (B-tile = 256 w1t rows: a-half rows 0..127, b-half rows 128..255). BK=64.
// 8 waves (2M x 4N): wave owns 128 rows x 32 f-pairs (both halves).
__global__ __launch_bounds__(512, 2) void gemm1_kernel(
    const unsigned short* __restrict__ xb, const unsigned short* __restrict__ w1t,
    const int* __restrict__ counts, const int* __restrict__ offs,
    const int* __restrict__ rowlist, unsigned short* __restrict__ g) {
  int e = blockIdx.z, ft = blockIdx.y, mt = blockIdx.x;
  int ne = counts[e];
  if (mt * 256 >= ne) return;
  int base = offs[e];

  __shared__ unsigned short A_[2][256 * 64];
  __shared__ unsigned short Bt_[2][256 * 64];

  int tid = threadIdx.x;
  int l = tid & 63, w = tid >> 6;
  int quad = l >> 4, l15 = l & 15;
  int wmr = (w & 1) * 128;       // wave M offset
  int wn1 = (w >> 1) * 32;       // wave N offset (f-pairs within 128)

  // staging: round j covers rows j*64 + w*8 + (l>>3); chunk slot l&7 holds
  // global chunk (l&7)^(l>>3)  (row&7 == l>>3), so LDS slot (R,s) = chunk s^(R&7).
  int r8 = l >> 3, cg = (l & 7) ^ r8;
  const unsigned short* apt[4];
  const unsigned short* bpt[4];
#pragma unroll
  for (int j = 0; j < 4; j++) {
    int R = j * 64 + w * 8 + r8;
    int tok = rowlist[base + min(mt * 256 + R, ne - 1)];
    apt[j] = xb + (size_t)((tok & (S_ - 1)) * B_ + (tok >> 11)) * H_ + cg * 8;
    int brow = (R < 128) ? (ft * 128 + R) : (F_ + ft * 128 + (R - 128));
    bpt[j] = w1t + ((size_t)e * F2_ + brow) * H_ + cg * 8;
  }

  f32x4 aa[8][2], ab[8][2];
#pragma unroll
  for (int i = 0; i < 8; i++)
#pragma unroll
    for (int n = 0; n < 2; n++) {
      aa[i][n] = (f32x4){0.f, 0.f, 0.f, 0.f};
      ab[i][n] = (f32x4){0.f, 0.f, 0.f, 0.f};
    }

#define STG1(bf, kk) do {                                         \
    _Pragma("unroll")                                             \
    for (int j = 0; j < 4; j++) {                                 \
      gld16(apt[j] + (kk), &A_[bf][(j * 64 + w * 8) * 64]);       \
      gld16(bpt[j] + (kk), &Bt_[bf][(j * 64 + w * 8) * 64]);      \
    } } while (0)

  STG1(0, 0);
  STG1(1, 64);

  const int NS = H_ / 64;   // 32
  for (int t = 0; t < NS; ++t) {
    int buf = t & 1;
    if (t < NS - 1) { WAITV8; } else { WAITV0; }
    SB(); SCB();
    const unsigned short* Ab = &A_[buf][0];
    const unsigned short* Bb = &Bt_[buf][0];

    // ---- k-slice 0 (chunks quad) ----
    s16x8 b0a[2], b0b[2];
#pragma unroll
    for (int n = 0; n < 2; n++) {
      b0a[n] = ldfrag(Bb, wn1 + n * 16 + l15, quad);
      b0b[n] = ldfrag(Bb, 128 + wn1 + n * 16 + l15, quad);
    }
    s16x8 af0[4];
#pragma unroll
    for (int i = 0; i < 4; i++) af0[i] = ldfrag(Ab, wmr + i * 16 + l15, quad);
    __builtin_amdgcn_s_setprio(1);
#pragma unroll
    for (int i = 0; i < 4; i++)
#pragma unroll
      for (int n = 0; n < 2; n++) {
        aa[i][n] = __builtin_amdgcn_mfma_f32_16x16x32_bf16(af0[i], b0a[n], aa[i][n], 0, 0, 0);
        ab[i][n] = __builtin_amdgcn_mfma_f32_16x16x32_bf16(af0[i], b0b[n], ab[i][n], 0, 0, 0);
      }
    __builtin_amdgcn_s_setprio(0);
    s16x8 af1[4];
#pragma unroll
    for (int i = 0; i < 4; i++) af1[i] = ldfrag(Ab, wmr + (4 + i) * 16 + l15, quad);
    __builtin_amdgcn_s_setprio(1);
#pragma unroll
    for (int i = 0; i < 4; i++)
#pragma unroll
      for (int n = 0; n < 2; n++) {
        aa[4 + i][n] = __builtin_amdgcn_mfma_f32_16x16x32_bf16(af1[i], b0a[n], aa[4 + i][n], 0, 0, 0);
        ab[4 + i][n] = __builtin_amdgcn_mfma_f32_16x16x32_bf16(af1[i], b0b[n], ab[4 + i][n], 0, 0, 0);
      }
    __builtin_amdgcn_s_setprio(0);

    // ---- k-slice 1 (chunks 4+quad) ----
    s16x8 b1a[2], b1b[2];
#pragma unroll
    for (int n = 0; n < 2; n++) {
      b1a[n] = ldfrag(Bb, wn1 + n * 16 + l15, 4 + quad);
      b1b[n] = ldfrag(Bb, 128 + wn1 + n * 16 + l15, 4 + quad);
    }
    s16x8 af2[4];
#pragma unroll
    for (int i = 0; i < 4; i++) af2[i] = ldfrag(Ab, wmr + i * 16 + l15, 4 + quad);
    __builtin_amdgcn_s_setprio(1);
#pragma unroll
    for (int i = 0; i < 4; i++)
#pragma unroll
      for (int n = 0; n < 2; n++) {
        aa[i][n] = __builtin_amdgcn_mfma_f32_16x16x32_bf16(af2[i], b1a[n], aa[i][n], 0, 0, 0);
        ab[i][n] = __builtin_amdgcn_mfma_f32_16x16x32_bf16(af2[i], b1b[n], ab[i][n], 0, 0, 0);
      }
    __builtin_amdgcn_s_setprio(0);
    s16x8 af3[4];
#pragma unroll
    for (int i = 0; i < 4; i++) af3[i] = ldfrag(Ab, wmr + (4 + i) * 16 + l15, 4 + quad);
    // all reads of this buffer issued; drain, join, then overwrite-stage
    LGKM0; SB(); SCB();
    if (t + 2 < NS) STG1(buf, (t + 2) * 64);
    __builtin_amdgcn_s_setprio(1);
#pragma unroll
    for (int i = 0; i < 4; i++)
#pragma unroll
      for (int n = 0; n < 2; n++) {
        aa[4 + i][n] = __builtin_amdgcn_mfma_f32_16x16x32_bf16(af3[i], b1a[n], aa[4 + i][n], 0, 0, 0);
        ab[4 + i][n] = __builtin_amdgcn_mfma_f32_16x16x32_bf16(af3[i], b1b[n], ab[4 + i][n], 0, 0, 0);
      }
    __builtin_amdgcn_s_setprio(0);
  }
#undef STG1

#pragma unroll
  for (int i = 0; i < 8; i++)
#pragma unroll
    for (int n = 0; n < 2; n++)
#pragma unroll
      for (int v = 0; v < 4; v++) {
        int row = wmr + i * 16 + quad * 4 + v;
        if (mt * 256 + row < ne) {
          int col = ft * 128 + wn1 + n * 16 + l15;
          float a = aa[i][n][v], bb = ab[i][n][v];
          float sg = a / (1.f + __expf(-a));
          g[(size_t)(base + mt * 256 + row) * F_ + col] = f2b(sg * bb);
        }
      }
}

// GEMM2: out[token] += rowwt * (g[slot,:] @ W2t[e]^T). grid (mt=32, nt=8, e=8).
// 256x256 tile, BK=64, 8 waves (2M x 4N): wave owns 128 x 64.
__global__ __launch_bounds__(512, 2) void gemm2_kernel(
    const unsigned short* __restrict__ g, const unsigned short* __restrict__ w2t,
    const int* __restrict__ counts, const int* __restrict__ offs,
    const int* __restrict__ rowlist, const float* __restrict__ rowwt,
    float* __restrict__ out) {
  int e = blockIdx.z, nt = blockIdx.y, mt = blockIdx.x;
  int ne = counts[e];
  if (mt * 256 >= ne) return;
  int base = offs[e];

  __shared__ unsigned short A_[2][256 * 64];
  __shared__ unsigned short Bt_[2][256 * 64];
  __shared__ float rwL[256];
  __shared__ int   toL[256];

  int tid = threadIdx.x;
  int l = tid & 63, w = tid >> 6;
  int quad = l >> 4, l15 = l & 15;
  int wmr = (w & 1) * 128;
  int wn2 = (w >> 1) * 64;

  int r8 = l >> 3, cg = (l & 7) ^ r8;
  const unsigned short* apt[4];
  const unsigned short* bpt[4];
#pragma unroll
  for (int j = 0; j < 4; j++) {
    int R = j * 64 + w * 8 + r8;
    int arow = min(mt * 256 + R, ne - 1);
    apt[j] = g + (size_t)(base + arow) * F_ + cg * 8;
    bpt[j] = w2t + ((size_t)e * H_ + nt * 256 + R) * F_ + cg * 8;
  }

  if (tid < 256) {
    int rr = min(mt * 256 + tid, ne - 1);
    rwL[tid] = rowwt[base + rr];
    int tk = rowlist[base + rr];
    toL[tid] = ((tk & (S_ - 1)) * B_ + (tk >> 11)) * H_;
  }

  f32x4 acc[8][4];
#pragma unroll
  for (int i = 0; i < 8; i++)
#pragma unroll
    for (int n = 0; n < 4; n++) acc[i][n] = (f32x4){0.f, 0.f, 0.f, 0.f};

#define STG2(bf, kk) do {                                         \
    _Pragma("unroll")                                             \
    for (int j = 0; j < 4; j++) {                                 \
      gld16(apt[j] + (kk), &A_[bf][(j * 64 + w * 8) * 64]);       \
      gld16(bpt[j] + (kk), &Bt_[bf][(j * 64 + w * 8) * 64]);      \
    } } while (0)

  STG2(0, 0);
  STG2(1, 64);

  const int NS = F_ / 64;   // 22
  for (int t = 0; t < NS; ++t) {
    int buf = t & 1;
    if (t < NS - 1) { WAITV8; } else { WAITV0; }
    SB(); SCB();
    const unsigned short* Ab = &A_[buf][0];
    const unsigned short* Bb = &Bt_[buf][0];

    // ---- k-slice 0 ----
    s16x8 b0[4];
#pragma unroll
    for (int n = 0; n < 4; n++) b0[n] = ldfrag(Bb, wn2 + n * 16 + l15, quad);
    s16x8 af0[4];
#pragma unroll
    for (int i = 0; i < 4; i++) af0[i] = ldfrag(Ab, wmr + i * 16 + l15, quad);
    __builtin_amdgcn_s_setprio(1);
#pragma unroll
    for (int i = 0; i < 4; i++)
#pragma unroll
      for (int n = 0; n < 4; n++)
        acc[i][n] = __builtin_amdgcn_mfma_f32_16x16x32_bf16(af0[i], b0[n], acc[i][n], 0, 0, 0);
    __builtin_amdgcn_s_setprio(0);
    s16x8 af1[4];
#pragma unroll
    for (int i = 0; i < 4; i++) af1[i] = ldfrag(Ab, wmr + (4 + i) * 16 + l15, quad);
    __builtin_amdgcn_s_setprio(1);
#pragma unroll
    for (int i = 0; i < 4; i++)
#pragma unroll
      for (int n = 0; n < 4; n++)
        acc[4 + i][n] = __builtin_amdgcn_mfma_f32_16x16x32_bf16(af1[i], b0[n], acc[4 + i][n], 0, 0, 0);
    __builtin_amdgcn_s_setprio(0);

    // ---- k-slice 1 ----
    s16x8 b1[4];
#pragma unroll
    for (int n = 0; n < 4; n++) b1[n] = ldfrag(Bb, wn2 + n * 16 + l15, 4 + quad);
    s16x8 af2[4];
#pragma unroll
    for (int i = 0; i < 4; i++) af2[i] = ldfrag(Ab, wmr + i * 16 + l15, 4 + quad);
    __builtin_amdgcn_s_setprio(1);
#pragma unroll
    for (int i = 0; i < 4; i++)
#pragma unroll
      for (int n = 0; n < 4; n++)
        acc[i][n] = __builtin_amdgcn_mfma_f32_16x16x32_bf16(af2[i], b1[n], acc[i][n], 0, 0, 0);
    __builtin_amdgcn_s_setprio(0);
    s16x8 af3[4];
#pragma unroll
    for (int i = 0; i < 4; i++) af3[i] = ldfrag(Ab, wmr + (4 + i) * 16 + l15, 4 + quad);
    LGKM0; SB(); SCB();
    if (t + 2 < NS) STG2(buf, (t + 2) * 64);
    __builtin_amdgcn_s_setprio(1);
#pragma unroll
    for (int i = 0; i < 4; i++)
#pragma unroll
      for (int n = 0; n < 4; n++)
        acc[4 + i][n] = __builtin_amdgcn_mfma_f32_16x16x32_bf16(af3[i], b1[n], acc[4 + i][n], 0, 0, 0);
    __builtin_amdgcn_s_setprio(0);
  }
#undef STG2

#pragma unroll
  for (int i = 0; i < 8; i++)
#pragma unroll
    for (int n = 0; n < 4; n++)
#pragma unroll
      for (int v = 0; v < 4; v++) {
        int row = wmr + i * 16 + quad * 4 + v;
        if (mt * 256 + row < ne) {
          int col = nt * 256 + wn2 + n * 16 + l15;
          atomicAdd(&out[(size_t)toL[row] + col], acc[i][n][v] * rwL[row]);
        }
      }
}

extern "C" void kernel_launch(void* const* d_in, const int* in_sizes, int n_in,
                              void* d_out, int out_size, void* d_ws, size_t ws_size,
                              hipStream_t stream) {
  const float* x  = (const float*)d_in[0];
  const float* wg = (const float*)d_in[1];
  const float* w1 = (const float*)d_in[2];
  const float* w2 = (const float*)d_in[3];
  float* out = (float*)d_out;

  char* ws = (char*)d_ws;
  int*   counts  = (int*)(ws + 0);
  int*   cursor  = (int*)(ws + 32);
  int*   offs    = (int*)(ws + 64);
  int*   eidx    = (int*)(ws + 128);
  float* ewt     = (float*)(ws + 65664);
  int*   rowlist = (int*)(ws + 131200);
  float* rowwt   = (float*)(ws + 196736);
  unsigned short* g   = (unsigned short*)(ws + 262272);
  unsigned short* xb  = (unsigned short*)(ws + 46399616);
  unsigned short* w1t = (unsigned short*)(ws + 79954048);
  unsigned short* w2t = (unsigned short*)(ws + 172228736);

  hipMemsetAsync(d_out, 0, (size_t)out_size * sizeof(float), stream);
  zero_kernel<<<1, 64, 0, stream>>>((int*)ws);
  cvt_kernel<<<T_ * H_ / 8 / 256, 256, 0, stream>>>(x, xb, T_ * H_ / 8);
  tcvt_kernel<<<dim3(F2_ / 64, H_ / 64, E_), 256, 0, stream>>>(w1, w1t, H_, F2_);
  tcvt_kernel<<<dim3(H_ / 64, F_ / 64, E_), 256, 0, stream>>>(w2, w2t, F_, H_);
  gate_kernel<<<T_ / 4, 256, 0, stream>>>(x, wg, counts, eidx, ewt);
  scan_kernel<<<1, 64, 0, stream>>>(counts, offs);
  assign_kernel<<<T_ / 256, 256, 0, stream>>>(eidx, ewt, offs, cursor, rowlist, rowwt);
  gemm1_kernel<<<dim3(32, F_ / 128, E_), 512, 0, stream>>>(xb, w1t, counts, offs, rowlist, g);
  gemm2_kernel<<<dim3(32, H_ / 256, E_), 512, 0, stream>>>(g, w2t, counts, offs, rowlist, rowwt, out);
}

// Round 4
// 1388.641 us; speedup vs baseline: 1.3587x; 1.3587x over previous
//
#include <hip/hip_runtime.h>
#include <hip/hip_bf16.h>
#include <cstdint>
#include <cstddef>

// Inputs fp32, output fp32. Internal bf16 MFMA.
// R4: R1's 4-wave 128-row-tile geometry (2 blocks/CU for inter-block latency
// cover) + BK=64 with the R3-verified zero-conflict XOR swizzle (slot = chunk
// ^ (row&7), both-sides) + counted vmcnt(8) double-buffer pipeline.
// cvt_kernel folded into gate_kernel (x read once).

#define S_ 2048
#define B_ 4
#define H_ 2048
#define F_ 1408
#define F2_ 2816
#define E_ 8
#define T_ 8192

typedef float f32x4 __attribute__((ext_vector_type(4)));
typedef short s16x8 __attribute__((ext_vector_type(8)));

#define WAITV8 asm volatile("s_waitcnt vmcnt(8)" ::: "memory")
#define WAITV0 asm volatile("s_waitcnt vmcnt(0)" ::: "memory")
#define LGKM0  asm volatile("s_waitcnt lgkmcnt(0)" ::: "memory")
#define SB()   __builtin_amdgcn_s_barrier()
#define SCB()  __builtin_amdgcn_sched_barrier(0)

__device__ __forceinline__ unsigned short f2b(float f) {
  union { unsigned int i; float f; } v; v.f = f;
  unsigned int r = v.i + 0x7FFFu + ((v.i >> 16) & 1u);
  return (unsigned short)(r >> 16);
}
__device__ __forceinline__ unsigned int pkbf(float lo, float hi) {
  __hip_bfloat162 h2 = __float22bfloat162_rn(make_float2(lo, hi));
  union { __hip_bfloat162 v; unsigned int u; } c; c.v = h2; return c.u;
}
__device__ __forceinline__ void gld16(const unsigned short* gp, unsigned short* lp) {
  __builtin_amdgcn_global_load_lds(
      (const __attribute__((address_space(1))) unsigned int*)gp,
      (__attribute__((address_space(3))) unsigned int*)lp, 16, 0, 0);
}
// swizzled fragment read: row r (128B rows), 16B-chunk c (0..7); slot = c ^ (r&7)
__device__ __forceinline__ s16x8 ldfrag(const unsigned short* base, int r, int c) {
  return *(const s16x8*)((const char*)base + r * 128 + (((c) ^ (r & 7)) << 4));
}

// ---------------- workspace layout (bytes) ----------------
// 0       : int counts[8]; 32: cursor[8]; 64: offs[8]
// 128     : int   eidx[2T]
// 65664   : float ewt[2T]
// 131200  : int   rowlist[2T]
// 196736  : float rowwt[2T]
// 262272  : bf16  g[2T][F]            (46137344)
// 46399616: bf16  xb[T][H]            (33554432)
// 79954048: bf16  w1t[E][2F][H]       (92274688)   k-major
// 172228736: bf16 w2t[E][H][F]        (46137344)   k-major
// total ~218.4 MB

__global__ void zero_kernel(int* ws_i) {
  if (threadIdx.x < 16) ws_i[threadIdx.x] = 0;
}

// src[e][r][c] fp32 -> dst[e][c][r] bf16.  64x64 tiles, dims % 64 == 0.
__global__ __launch_bounds__(256) void tcvt_kernel(
    const float* __restrict__ src, unsigned short* __restrict__ dst,
    int rows, int cols) {
  int e = blockIdx.z;
  int c0 = blockIdx.x * 64, r0 = blockIdx.y * 64;
  const float* s = src + (size_t)e * rows * cols;
  unsigned short* d = dst + (size_t)e * rows * cols;
  __shared__ unsigned short Lt[64][72];
  int tid = threadIdx.x;
  int cl = tid & 63, w = tid >> 6;
#pragma unroll
  for (int i = 0; i < 16; i++) {
    int r = w * 16 + i;
    Lt[cl][r] = f2b(s[(size_t)(r0 + r) * cols + c0 + cl]);
  }
  __syncthreads();
  int cc = tid >> 3, hc = tid & 7;
#pragma unroll
  for (int j = 0; j < 2; j++) {
    int c = cc + j * 32;
    *(uint4*)&d[(size_t)(c0 + c) * rows + r0 + hc * 8] = *(uint4*)&Lt[c][hc * 8];
  }
}

// one wave per token: fp32 logits over 8 experts, softmax, top-2.
// Also writes the bf16 copy of x (xb) — x is read exactly once.
__global__ __launch_bounds__(256) void gate_kernel(
    const float* __restrict__ x, const float* __restrict__ wg,
    int* __restrict__ counts, int* __restrict__ eidx, float* __restrict__ ewt,
    unsigned short* __restrict__ xb) {
  int wave = threadIdx.x >> 6, lane = threadIdx.x & 63;
  int t = blockIdx.x * 4 + wave;
  int b = t >> 11, s = t & (S_ - 1);
  size_t rowoff = (size_t)(s * B_ + b) * H_;
  const float* xrow = x + rowoff;
  unsigned short* xbrow = xb + rowoff;
  float acc[E_];
#pragma unroll
  for (int e = 0; e < E_; e++) acc[e] = 0.f;
  for (int h0 = lane * 4; h0 < H_; h0 += 256) {
    f32x4 xa = *(const f32x4*)(xrow + h0);
    uint2 u;
    u.x = pkbf(xa[0], xa[1]);
    u.y = pkbf(xa[2], xa[3]);
    *(uint2*)(xbrow + h0) = u;
#pragma unroll
    for (int e = 0; e < E_; e++) {
      f32x4 wa = *(const f32x4*)(wg + e * H_ + h0);
      acc[e] += xa[0] * wa[0] + xa[1] * wa[1] + xa[2] * wa[2] + xa[3] * wa[3];
    }
  }
#pragma unroll
  for (int e = 0; e < E_; e++)
    for (int off = 32; off; off >>= 1) acc[e] += __shfl_xor(acc[e], off, 64);
  if (lane == 0) {
    float m = acc[0];
#pragma unroll
    for (int e = 1; e < E_; e++) m = fmaxf(m, acc[e]);
    float ex[E_], ssum = 0.f;
#pragma unroll
    for (int e = 0; e < E_; e++) { ex[e] = __expf(acc[e] - m); ssum += ex[e]; }
    float sc[E_];
#pragma unroll
    for (int e = 0; e < E_; e++) sc[e] = ex[e] / ssum;
    int i1 = 0;
#pragma unroll
    for (int e = 1; e < E_; e++) if (sc[e] > sc[i1]) i1 = e;
    int i2 = (i1 == 0) ? 1 : 0;
#pragma unroll
    for (int e = 0; e < E_; e++) if (e != i1 && sc[e] > sc[i2]) i2 = e;
    float wsum = sc[i1] + sc[i2] + 1e-20f;
    eidx[2 * t] = i1;     ewt[2 * t] = sc[i1] / wsum;
    eidx[2 * t + 1] = i2; ewt[2 * t + 1] = sc[i2] / wsum;
    atomicAdd(&counts[i1], 1);
    atomicAdd(&counts[i2], 1);
  }
}

__global__ void scan_kernel(const int* __restrict__ counts, int* __restrict__ offs) {
  if (threadIdx.x == 0) {
    int run = 0;
    for (int e = 0; e < E_; e++) { offs[e] = run; run += counts[e]; }
  }
}

__global__ void assign_kernel(const int* __restrict__ eidx, const float* __restrict__ ewt,
                              const int* __restrict__ offs, int* __restrict__ cursor,
                              int* __restrict__ rowlist, float* __restrict__ rowwt) {
  int t = blockIdx.x * 256 + threadIdx.x;
  if (t >= T_) return;
#pragma unroll
  for (int k = 0; k < 2; k++) {
    int e = eidx[2 * t + k];
    int pos = atomicAdd(&cursor[e], 1);
    int slot = offs[e] + pos;
    rowlist[slot] = t;
    rowwt[slot] = ewt[2 * t + k];
  }
}

// GEMM1 + swiglu. grid (rt=64, ft=22, e=8). Tile 128 rows x 64 f-pairs, BK=64.
// 4 waves (2M x 2N). Double-buffered, counted vmcnt(8), swizzled LDS.
__global__ __launch_bounds__(256, 2) void gemm1_kernel(
    const unsigned short* __restrict__ xb, const unsigned short* __restrict__ w1t,
    const int* __restrict__ counts, const int* __restrict__ offs,
    const int* __restrict__ rowlist, unsigned short* __restrict__ g) {
  int e = blockIdx.z, ft = blockIdx.y, rt = blockIdx.x;
  int ne = counts[e];
  if (rt * 128 >= ne) return;
  int base = offs[e];

  __shared__ unsigned short A_[2][128 * 64];
  __shared__ unsigned short Ba_[2][64 * 64];
  __shared__ unsigned short Bb_[2][64 * 64];

  int tid = threadIdx.x;
  int l = tid & 63, w = tid >> 6;
  int quad = l >> 4, l15 = l & 15;
  int wm = (w & 1) * 64, wn = (w >> 1) * 32;

  // staging: lane l covers row-group r8 = l>>3, chunk slot l&7 holds global
  // chunk (l&7)^r8; row R = j*32 + w*8 + r8 (R&7 == r8). LDS write is linear.
  int r8 = l >> 3, cg = (l & 7) ^ r8;
  const unsigned short* apt[4];
  const unsigned short* bpa[2];
  const unsigned short* bpb[2];
#pragma unroll
  for (int j = 0; j < 4; j++) {
    int R = j * 32 + w * 8 + r8;
    int tok = rowlist[base + min(rt * 128 + R, ne - 1)];
    apt[j] = xb + (size_t)((tok & (S_ - 1)) * B_ + (tok >> 11)) * H_ + cg * 8;
  }
#pragma unroll
  for (int j = 0; j < 2; j++) {
    int R = j * 32 + w * 8 + r8;
    bpa[j] = w1t + ((size_t)e * F2_ + ft * 64 + R) * H_ + cg * 8;
    bpb[j] = bpa[j] + (size_t)F_ * H_;
  }

  f32x4 acc[2][4][2];
#pragma unroll
  for (int h2 = 0; h2 < 2; h2++)
    for (int i = 0; i < 4; i++)
      for (int j = 0; j < 2; j++) acc[h2][i][j] = (f32x4){0.f, 0.f, 0.f, 0.f};

#define STG1(bf, kk) do {                                           \
    _Pragma("unroll")                                               \
    for (int j = 0; j < 4; j++)                                     \
      gld16(apt[j] + (kk), &A_[bf][(j * 32 + w * 8) * 64]);         \
    _Pragma("unroll")                                               \
    for (int j = 0; j < 2; j++) {                                   \
      gld16(bpa[j] + (kk), &Ba_[bf][(j * 32 + w * 8) * 64]);        \
      gld16(bpb[j] + (kk), &Bb_[bf][(j * 32 + w * 8) * 64]);        \
    } } while (0)

  STG1(0, 0);
  STG1(1, 64);

  const int NS = H_ / 64;   // 32
  for (int t = 0; t < NS; ++t) {
    int buf = t & 1;
    if (t < NS - 1) { WAITV8; } else { WAITV0; }
    SB(); SCB();
    const unsigned short* Ab = &A_[buf][0];
    const unsigned short* Bab = &Ba_[buf][0];
    const unsigned short* Bbb = &Bb_[buf][0];

    // ---- k-slice 0 (chunk quad) ----
    s16x8 ba0[2], bb0[2];
#pragma unroll
    for (int n = 0; n < 2; n++) {
      ba0[n] = ldfrag(Bab, wn + n * 16 + l15, quad);
      bb0[n] = ldfrag(Bbb, wn + n * 16 + l15, quad);
    }
    s16x8 af0[4];
#pragma unroll
    for (int i = 0; i < 4; i++) af0[i] = ldfrag(Ab, wm + i * 16 + l15, quad);
    __builtin_amdgcn_s_setprio(1);
#pragma unroll
    for (int i = 0; i < 4; i++)
#pragma unroll
      for (int n = 0; n < 2; n++) {
        acc[0][i][n] = __builtin_amdgcn_mfma_f32_16x16x32_bf16(af0[i], ba0[n], acc[0][i][n], 0, 0, 0);
        acc[1][i][n] = __builtin_amdgcn_mfma_f32_16x16x32_bf16(af0[i], bb0[n], acc[1][i][n], 0, 0, 0);
      }
    __builtin_amdgcn_s_setprio(0);

    // ---- k-slice 1 (chunk 4+quad) ----
    s16x8 ba1[2], bb1[2];
#pragma unroll
    for (int n = 0; n < 2; n++) {
      ba1[n] = ldfrag(Bab, wn + n * 16 + l15, 4 + quad);
      bb1[n] = ldfrag(Bbb, wn + n * 16 + l15, 4 + quad);
    }
    s16x8 af1[4];
#pragma unroll
    for (int i = 0; i < 4; i++) af1[i] = ldfrag(Ab, wm + i * 16 + l15, 4 + quad);
    // all reads of this buffer issued; drain, join, overwrite-stage
    LGKM0; SB(); SCB();
    if (t + 2 < NS) STG1(buf, (t + 2) * 64);
    __builtin_amdgcn_s_setprio(1);
#pragma unroll
    for (int i = 0; i < 4; i++)
#pragma unroll
      for (int n = 0; n < 2; n++) {
        acc[0][i][n] = __builtin_amdgcn_mfma_f32_16x16x32_bf16(af1[i], ba1[n], acc[0][i][n], 0, 0, 0);
        acc[1][i][n] = __builtin_amdgcn_mfma_f32_16x16x32_bf16(af1[i], bb1[n], acc[1][i][n], 0, 0, 0);
      }
    __builtin_amdgcn_s_setprio(0);
  }
#undef STG1

#pragma unroll
  for (int i = 0; i < 4; i++)
#pragma unroll
    for (int n = 0; n < 2; n++)
#pragma unroll
      for (int v = 0; v < 4; v++) {
        int row = wm + i * 16 + quad * 4 + v;
        if (rt * 128 + row < ne) {
          int col = ft * 64 + wn + n * 16 + l15;
          float a = acc[0][i][n][v], bb = acc[1][i][n][v];
          float sg = a / (1.f + __expf(-a));
          g[(size_t)(base + rt * 128 + row) * F_ + col] = f2b(sg * bb);
        }
      }
}

// GEMM2: out[token] += rowwt * (g[slot,:] @ W2t[e]^T).  grid (64, 16, 8).
// 128x128 tile, BK=64, 4 waves, swizzled double-buffered pipeline.
__global__ __launch_bounds__(256, 2) void gemm2_kernel(
    const unsigned short* __restrict__ g, const unsigned short* __restrict__ w2t,
    const int* __restrict__ counts, const int* __restrict__ offs,
    const int* __restrict__ rowlist, const float* __restrict__ rowwt,
    float* __restrict__ out) {
  int e = blockIdx.z, nt = blockIdx.y, rt = blockIdx.x;
  int ne = counts[e];
  if (rt * 128 >= ne) return;
  int base = offs[e];

  __shared__ unsigned short A_[2][128 * 64];
  __shared__ unsigned short Bt_[2][128 * 64];
  __shared__ float rwL[128];
  __shared__ int   toL[128];

  int tid = threadIdx.x;
  int l = tid & 63, w = tid >> 6;
  int quad = l >> 4, l15 = l & 15;
  int wm = (w & 1) * 64, wn = (w >> 1) * 64;

  int r8 = l >> 3, cg = (l & 7) ^ r8;
  const unsigned short* apt[4];
  const unsigned short* bpt[4];
#pragma unroll
  for (int j = 0; j < 4; j++) {
    int R = j * 32 + w * 8 + r8;
    int arow = min(rt * 128 + R, ne - 1);
    apt[j] = g + (size_t)(base + arow) * F_ + cg * 8;
    bpt[j] = w2t + ((size_t)e * H_ + nt * 128 + R) * F_ + cg * 8;
  }

  if (tid < 128) {
    int rr = min(rt * 128 + tid, ne - 1);
    rwL[tid] = rowwt[base + rr];
    int tk = rowlist[base + rr];
    toL[tid] = ((tk & (S_ - 1)) * B_ + (tk >> 11)) * H_;
  }

  f32x4 acc[4][4];
#pragma unroll
  for (int i = 0; i < 4; i++)
    for (int j = 0; j < 4; j++) acc[i][j] = (f32x4){0.f, 0.f, 0.f, 0.f};

#define STG2(bf, kk) do {                                           \
    _Pragma("unroll")                                               \
    for (int j = 0; j < 4; j++) {                                   \
      gld16(apt[j] + (kk), &A_[bf][(j * 32 + w * 8) * 64]);         \
      gld16(bpt[j] + (kk), &Bt_[bf][(j * 32 + w * 8) * 64]);        \
    } } while (0)

  STG2(0, 0);
  STG2(1, 64);

  const int NS = F_ / 64;   // 22
  for (int t = 0; t < NS; ++t) {
    int buf = t & 1;
    if (t < NS - 1) { WAITV8; } else { WAITV0; }
    SB(); SCB();
    const unsigned short* Ab = &A_[buf][0];
    const unsigned short* Bb = &Bt_[buf][0];

    // ---- k-slice 0 ----
    s16x8 b0[4];
#pragma unroll
    for (int n = 0; n < 4; n++) b0[n] = ldfrag(Bb, wn + n * 16 + l15, quad);
    s16x8 af0[4];
#pragma unroll
    for (int i = 0; i < 4; i++) af0[i] = ldfrag(Ab, wm + i * 16 + l15, quad);
    __builtin_amdgcn_s_setprio(1);
#pragma unroll
    for (int i = 0; i < 4; i++)
#pragma unroll
      for (int n = 0; n < 4; n++)
        acc[i][n] = __builtin_amdgcn_mfma_f32_16x16x32_bf16(af0[i], b0[n], acc[i][n], 0, 0, 0);
    __builtin_amdgcn_s_setprio(0);

    // ---- k-slice 1 ----
    s16x8 b1[4];
#pragma unroll
    for (int n = 0; n < 4; n++) b1[n] = ldfrag(Bb, wn + n * 16 + l15, 4 + quad);
    s16x8 af1[4];
#pragma unroll
    for (int i = 0; i < 4; i++) af1[i] = ldfrag(Ab, wm + i * 16 + l15, 4 + quad);
    LGKM0; SB(); SCB();
    if (t + 2 < NS) STG2(buf, (t + 2) * 64);
    __builtin_amdgcn_s_setprio(1);
#pragma unroll
    for (int i = 0; i < 4; i++)
#pragma unroll
      for (int n = 0; n < 4; n++)
        acc[i][n] = __builtin_amdgcn_mfma_f32_16x16x32_bf16(af1[i], b1[n], acc[i][n], 0, 0, 0);
    __builtin_amdgcn_s_setprio(0);
  }
#undef STG2

#pragma unroll
  for (int i = 0; i < 4; i++)
#pragma unroll
    for (int n = 0; n < 4; n++)
#pragma unroll
      for (int v = 0; v < 4; v++) {
        int row = wm + i * 16 + quad * 4 + v;
        if (rt * 128 + row < ne) {
          int col = nt * 128 + wn + n * 16 + l15;
          atomicAdd(&out[(size_t)toL[row] + col], acc[i][n][v] * rwL[row]);
        }
      }
}

extern "C" void kernel_launch(void* const* d_in, const int* in_sizes, int n_in,
                              void* d_out, int out_size, void* d_ws, size_t ws_size,
                              hipStream_t stream) {
  const float* x  = (const float*)d_in[0];
  const float* wg = (const float*)d_in[1];
  const float* w1 = (const float*)d_in[2];
  const float* w2 = (const float*)d_in[3];
  float* out = (float*)d_out;

  char* ws = (char*)d_ws;
  int*   counts  = (int*)(ws + 0);
  int*   cursor  = (int*)(ws + 32);
  int*   offs    = (int*)(ws + 64);
  int*   eidx    = (int*)(ws + 128);
  float* ewt     = (float*)(ws + 65664);
  int*   rowlist = (int*)(ws + 131200);
  float* rowwt   = (float*)(ws + 196736);
  unsigned short* g   = (unsigned short*)(ws + 262272);
  unsigned short* xb  = (unsigned short*)(ws + 46399616);
  unsigned short* w1t = (unsigned short*)(ws + 79954048);
  unsigned short* w2t = (unsigned short*)(ws + 172228736);

  hipMemsetAsync(d_out, 0, (size_t)out_size * sizeof(float), stream);
  zero_kernel<<<1, 64, 0, stream>>>((int*)ws);
  tcvt_kernel<<<dim3(F2_ / 64, H_ / 64, E_), 256, 0, stream>>>(w1, w1t, H_, F2_);
  tcvt_kernel<<<dim3(H_ / 64, F_ / 64, E_), 256, 0, stream>>>(w2, w2t, F_, H_);
  gate_kernel<<<T_ / 4, 256, 0, stream>>>(x, wg, counts, eidx, ewt, xb);
  scan_kernel<<<1, 64, 0, stream>>>(counts, offs);
  assign_kernel<<<T_ / 256, 256, 0, stream>>>(eidx, ewt, offs, cursor, rowlist, rowwt);
  gemm1_kernel<<<dim3(64, 22, E_), 256, 0, stream>>>(xb, w1t, counts, offs, rowlist, g);
  gemm2_kernel<<<dim3(64, 16, E_), 256, 0, stream>>>(g, w2t, counts, offs, rowlist, rowwt, out);
}